// Round 14
// baseline (113.941 us; speedup 1.0000x reference)
//
#include <hip/hip_runtime.h>

// Problem dims (fixed by setup_inputs): x [B,N,C], adapter dim D, patch grid HxH
#define B_  64
#define N_  1024
#define H_  32
#define C_  768
#define D_  8

#define QCHUNKS    4
#define IMG_PER_Q  (B_ / QCHUNKS)          // 16 images per chunk
#define ROWS_PER_Q (IMG_PER_Q * N_)        // 16384 rows
#define NDOWN      512                     // 32 rows each
#define NCONV      (IMG_PER_Q * 4)         // 64: one strip each
#define NUPB       256                     // 64 rows each -> full write spread

__device__ __forceinline__ float qgelu(float v) {
    return v / (1.0f + __expf(-1.702f * v));
}

typedef float f32x4_t __attribute__((ext_vector_type(4)));
__device__ __forceinline__ float4 ntload4(const float4* p) {
    f32x4_t v = __builtin_nontemporal_load((const f32x4_t*)p);
    return make_float4(v.x, v.y, v.z, v.w);
}
__device__ __forceinline__ void ntstore4(float4 v, float4* p) {
    f32x4_t t; t.x = v.x; t.y = v.y; t.z = v.z; t.w = v.w;
    __builtin_nontemporal_store(t, (f32x4_t*)p);
}

// 10-shuffle butterfly reduce over d=8 (see earlier rounds).
__device__ __forceinline__ void reduce8(float* acc, int lane) {
    {
        const bool hi = lane & 1;
#pragma unroll
        for (int j = 0; j < 4; ++j) {
            const float a = acc[j], b = acc[j + 4];
            acc[j] = hi ? b : a;
            acc[j + 4] = hi ? a : b;
        }
#pragma unroll
        for (int j = 0; j < 4; ++j)
            acc[j] += __shfl_xor(acc[j + 4], 1, 64);
    }
    {
        const bool hi = lane & 2;
#pragma unroll
        for (int j = 0; j < 2; ++j) {
            const float a = acc[j], b = acc[j + 2];
            acc[j] = hi ? b : a;
            acc[j + 2] = hi ? a : b;
        }
#pragma unroll
        for (int j = 0; j < 2; ++j)
            acc[j] += __shfl_xor(acc[j + 2], 2, 64);
    }
    {
        const bool hi = lane & 4;
        const float a = acc[0], b = acc[1];
        acc[0] = hi ? b : a;
        acc[1] = hi ? a : b;
        acc[0] += __shfl_xor(acc[1], 4, 64);
    }
    acc[0] += __shfl_xor(acc[0], 8, 64);
    acc[0] += __shfl_xor(acc[0], 16, 64);
    acc[0] += __shfl_xor(acc[0], 32, 64);
}

// ---------------- k_step: 3-stage software pipeline --------------------------
// Block roles by index (ordered UP | DOWN | CONV so roles interleave on CUs):
//  UP(upC):    256 blocks x 64 rows — Wu from LDS (2-row amortized ds reads),
//              nt stores of out. Full 256-CU write spread.
//  DOWN(downC): 512 blocks x 32 rows — v12 structure (nt x loads, LDS-
//              transposed Wd, reduce8).
//  CONV(convC): 64 blocks x 1 strip — conv3x3+bias+qgelu t1->t2 (global ws).
// Roles touch disjoint data; launches are stream-ordered so chunk deps hold.
__global__ __launch_bounds__(256) void k_step(
    const float* __restrict__ x,  const float* __restrict__ Wd,
    const float* __restrict__ bd, float* __restrict__ t1,
    const float* __restrict__ Wc, const float* __restrict__ bc,
    float* __restrict__ t2,       const float* __restrict__ Wu,
    const float* __restrict__ bu, float* __restrict__ out,
    int nUp, int upC, int nDown, int downC, int nConv, int convC)
{
    __shared__ float smem[D_ * C_];          // 24 KB, role-dependent layout
    const int wid  = threadIdx.x >> 6;
    const int lane = threadIdx.x & 63;
    const int bid  = blockIdx.x;

    if (bid < nUp) {
        // --------------------------- UP role ------------------------------
        float* sW = smem;                    // Wu is [D][C] row-major: direct
        for (int i = threadIdx.x; i < D_ * C_; i += 256) sW[i] = Wu[i];
        __syncthreads();

        float4 ub[3];
#pragma unroll
        for (int j = 0; j < 3; ++j)
            ub[j] = *(const float4*)&bu[(lane + j * 64) * 4];

        const int rowBase = upC * ROWS_PER_Q + bid * 64 + wid * 16;
#pragma unroll 1
        for (int pr = 0; pr < 8; ++pr) {
            const int row = rowBase + pr * 2;
            const float4* rp = (const float4*)(t2 + (size_t)row * D_);
            const float4 r0a = rp[0], r0b = rp[1];   // row
            const float4 r1a = rp[2], r1b = rp[3];   // row+1
            const float rv0[D_] = { r0a.x,r0a.y,r0a.z,r0a.w, r0b.x,r0b.y,r0b.z,r0b.w };
            const float rv1[D_] = { r1a.x,r1a.y,r1a.z,r1a.w, r1b.x,r1b.y,r1b.z,r1b.w };

            float4 o0[3], o1[3];
#pragma unroll
            for (int j = 0; j < 3; ++j) { o0[j] = ub[j]; o1[j] = ub[j]; }
#pragma unroll
            for (int d = 0; d < D_; ++d) {
#pragma unroll
                for (int j = 0; j < 3; ++j) {
                    const float4 wv = *(const float4*)&sW[d * C_ + (lane + j * 64) * 4];
                    o0[j].x += rv0[d] * wv.x; o0[j].y += rv0[d] * wv.y;
                    o0[j].z += rv0[d] * wv.z; o0[j].w += rv0[d] * wv.w;
                    o1[j].x += rv1[d] * wv.x; o1[j].y += rv1[d] * wv.y;
                    o1[j].z += rv1[d] * wv.z; o1[j].w += rv1[d] * wv.w;
                }
            }
            float* orow0 = out + (size_t)row * C_;
#pragma unroll
            for (int j = 0; j < 3; ++j) {
                ntstore4(o0[j], (float4*)&orow0[(lane + j * 64) * 4]);
                ntstore4(o1[j], (float4*)&orow0[C_ + (lane + j * 64) * 4]);
            }
        }
    } else if (bid < nUp + nDown) {
        // -------------------------- DOWN role -----------------------------
        float* sW = smem;                    // sW[d*C_ + c] = Wd[c*D_ + d]
        for (int i = threadIdx.x; i < D_ * C_; i += 256) {
            const int c = i >> 3, d = i & 7;
            sW[d * C_ + c] = Wd[i];
        }
        __syncthreads();

        const int dl = 4 * (lane & 1) + 2 * ((lane >> 1) & 1) + ((lane >> 2) & 1);
        const float bias = bd[dl];
        const int pairBase = (downC * ROWS_PER_Q >> 1) + (bid - nUp) * 16 + wid * 4;

#pragma unroll 1
        for (int i = 0; i < 4; ++i) {
            const int p = pairBase + i;
            const float4* x0 = (const float4*)(x + (size_t)(2 * p) * C_);
            const float4* x1 = x0 + (C_ / 4);

            float4 va[3], vb[3];
#pragma unroll
            for (int k = 0; k < 3; ++k) {
                va[k] = ntload4(&x0[k * 64 + lane]);
                vb[k] = ntload4(&x1[k * 64 + lane]);
            }

            float a0[D_], a1[D_];
#pragma unroll
            for (int d = 0; d < D_; ++d) { a0[d] = 0.0f; a1[d] = 0.0f; }

#pragma unroll
            for (int k = 0; k < 3; ++k) {
#pragma unroll
                for (int d = 0; d < D_; ++d) {
                    const float4 wv = *(const float4*)&sW[d * C_ + (k * 64 + lane) * 4];
                    a0[d] += va[k].x * wv.x + va[k].y * wv.y
                           + va[k].z * wv.z + va[k].w * wv.w;
                    a1[d] += vb[k].x * wv.x + vb[k].y * wv.y
                           + vb[k].z * wv.z + vb[k].w * wv.w;
                }
            }
            reduce8(a0, lane);
            reduce8(a1, lane);
            if (lane < 16) {
                const float s = (lane & 8) ? a1[0] : a0[0];
                t1[(size_t)(2 * p + ((lane >> 3) & 1)) * D_ + dl] = qgelu(s + bias);
            }
        }
    } else {
        // -------------------------- CONV role -----------------------------
        float* sIn = smem;                   // [10][32][8] = 2560 floats
        float* sWc = smem + 2560;            // 576
        float* sbc = smem + 3136;            // 8

        const int idx   = bid - nUp - nDown;
        const int img   = convC * IMG_PER_Q + (idx >> 2);
        const int strip = idx & 3;
        const int h0    = strip * 8;
        const float* in = t1 + (size_t)img * N_ * D_;

#pragma unroll
        for (int j = 0; j < 10; ++j) {
            const int i   = threadIdx.x + j * 256;
            const int lr  = i >> 8;
            const int rem = i & 255;
            const int g   = h0 - 1 + lr;
            sIn[i] = (g >= 0 && g < H_) ? in[(size_t)g * H_ * D_ + rem] : 0.0f;
        }
        for (int i = threadIdx.x; i < 9 * D_ * D_; i += 256) sWc[i] = Wc[i];
        if (threadIdx.x < D_) sbc[threadIdx.x] = bc[threadIdx.x];
        __syncthreads();

        const int lh = threadIdx.x >> 5;
        const int w  = threadIdx.x & 31;
        float acc[D_];
#pragma unroll
        for (int co = 0; co < D_; ++co) acc[co] = sbc[co];
#pragma unroll
        for (int kh = 0; kh < 3; ++kh) {
            const int lrow = lh + kh;
#pragma unroll
            for (int kw = 0; kw < 3; ++kw) {
                const int ww = w + kw - 1;
                if (ww < 0 || ww >= H_) continue;
                const float* ip = &sIn[(lrow * H_ + ww) * D_];
                const float* wp = &sWc[(kh * 3 + kw) * D_ * D_];
#pragma unroll
                for (int ci = 0; ci < D_; ++ci) {
                    const float iv = ip[ci];
#pragma unroll
                    for (int co = 0; co < D_; ++co)
                        acc[co] += iv * wp[ci * D_ + co];
                }
            }
        }
        float4 o0, o1;
        o0.x = qgelu(acc[0]); o0.y = qgelu(acc[1]);
        o0.z = qgelu(acc[2]); o0.w = qgelu(acc[3]);
        o1.x = qgelu(acc[4]); o1.y = qgelu(acc[5]);
        o1.z = qgelu(acc[6]); o1.w = qgelu(acc[7]);
        float* tp = t2 + ((size_t)img * N_ + (size_t)(h0 + lh) * H_ + w) * D_;
        *(float4*)tp       = o0;    // cacheable: re-read by UP next launch
        *(float4*)(tp + 4) = o1;
    }
}

extern "C" void kernel_launch(void* const* d_in, const int* in_sizes, int n_in,
                              void* d_out, int out_size, void* d_ws, size_t ws_size,
                              hipStream_t stream) {
    const float* x  = (const float*)d_in[0];
    const float* Wd = (const float*)d_in[1];
    const float* bd = (const float*)d_in[2];
    const float* Wc = (const float*)d_in[3];
    const float* bc = (const float*)d_in[4];
    const float* Wu = (const float*)d_in[5];
    const float* bu = (const float*)d_in[6];
    float* out = (float*)d_out;

    const int nrows = B_ * N_;                  // 65536
    float* t1 = (float*)d_ws;                   // [nrows][D_] (2 MB)
    float* t2 = t1 + (size_t)nrows * D_;        // [nrows][D_] (2 MB)

    // 3-stage pipeline: launch s runs down(s) || conv(s-1) || up(s-2).
    for (int s = 0; s < QCHUNKS + 2; ++s) {
        const int nD = (s < QCHUNKS) ? NDOWN : 0;
        const int nC = (s >= 1 && s <= QCHUNKS) ? NCONV : 0;
        const int nU = (s >= 2) ? NUPB : 0;
        k_step<<<nU + nD + nC, 256, 0, stream>>>(
            x, Wd, bd, t1, Wc, bc, t2, Wu, bu, out,
            nU, s - 2, nD, s, nC, s - 1);
    }
}